// Round 9
// baseline (486.943 us; speedup 1.0000x reference)
//
#include <hip/hip_runtime.h>

typedef unsigned short ushort;
typedef unsigned int   uint;
typedef short bf16x8 __attribute__((ext_vector_type(8)));
typedef float f32x4  __attribute__((ext_vector_type(4)));

// ---------- helpers ----------
__device__ __forceinline__ float bf2f(ushort u){
  union { uint u; float f; } c; c.u = ((uint)u) << 16; return c.f;
}
__device__ __forceinline__ ushort f2bf(float f){
  union { float f; uint u; } c; c.f = f;
  return (ushort)((c.u + 0x7fffu + ((c.u >> 16) & 1u)) >> 16);
}
__device__ __forceinline__ float wredsum(float v){
  #pragma unroll
  for (int off = 32; off > 0; off >>= 1) v += __shfl_xor(v, off);
  return v;
}
__device__ __forceinline__ void gload16(const void* g, void* l){
  __builtin_amdgcn_global_load_lds((__attribute__((address_space(1))) void*)(void*)g,
                                   (__attribute__((address_space(3))) void*)l, 16, 0, 0);
}

// ---------- transpose f32 [R][C] -> bf16 [C][R] (optionally split hi/lo), per-z slice ----------
template<bool SPLIT>
__global__ __launch_bounds__(256) void transpose_to_bf16(
    const float* __restrict__ src, ushort* __restrict__ dhi, ushort* __restrict__ dlo,
    int R, int C)
{
  __shared__ float tile[32][33];
  size_t zoff = (size_t)blockIdx.z * R * C;
  src += zoff; dhi += zoff; if (SPLIT) dlo += zoff;
  int c0 = blockIdx.x * 32, r0 = blockIdx.y * 32;
  int tx = threadIdx.x & 31, ty = threadIdx.x >> 5;
  #pragma unroll
  for (int i = 0; i < 32; i += 8)
    tile[ty + i][tx] = src[(size_t)(r0 + ty + i) * C + (c0 + tx)];
  __syncthreads();
  #pragma unroll
  for (int i = 0; i < 32; i += 8){
    float v = tile[tx][ty + i];
    ushort hi = f2bf(v);
    dhi[(size_t)(c0 + ty + i) * R + (r0 + tx)] = hi;
    if constexpr (SPLIT)
      dlo[(size_t)(c0 + ty + i) * R + (r0 + tx)] = f2bf(v - bf2f(hi));
  }
}

// ---------- fused q/k/v weight transpose: [512,32] x16 heads x3 tensors -> split bf16 ----------
__global__ __launch_bounds__(256) void transpose_qkv(
    const float* __restrict__ wq, const float* __restrict__ wk, const float* __restrict__ wv,
    ushort* __restrict__ dhi, ushort* __restrict__ dlo)
{
  __shared__ float tile[32][33];
  int z = blockIdx.z;                 // 0..47
  int which = z >> 4, h = z & 15;
  const float* src = (which == 0) ? wq : (which == 1) ? wk : wv;
  size_t soff = (size_t)h * 512 * 32;
  size_t doff = (size_t)which * 262144 + soff;
  src += soff;
  int r0 = blockIdx.y * 32;
  int tx = threadIdx.x & 31, ty = threadIdx.x >> 5;
  #pragma unroll
  for (int i = 0; i < 32; i += 8)
    tile[ty + i][tx] = src[(size_t)(r0 + ty + i) * 32 + tx];
  __syncthreads();
  #pragma unroll
  for (int i = 0; i < 32; i += 8){
    float v = tile[tx][ty + i];
    ushort hi = f2bf(v);
    dhi[doff + (size_t)(ty + i) * 512 + (r0 + tx)] = hi;
    dlo[doff + (size_t)(ty + i) * 512 + (r0 + tx)] = f2bf(v - bf2f(hi));
  }
}

// ---------- LN1: x[N,512] f32 -> h split bf16 hi/lo ----------
__global__ __launch_bounds__(256) void ln_split(
    const float* __restrict__ x, const float* __restrict__ g, const float* __restrict__ b,
    ushort* __restrict__ hhi, ushort* __restrict__ hlo)
{
  int w = threadIdx.x >> 6, lane = threadIdx.x & 63;
  int row = blockIdx.x * 4 + w;
  const float* xr = x + (size_t)row * 512;
  int d = lane * 8;
  float4 a0 = *(const float4*)(xr + d);
  float4 a1 = *(const float4*)(xr + d + 4);
  float v[8] = {a0.x,a0.y,a0.z,a0.w,a1.x,a1.y,a1.z,a1.w};
  float s = 0.f;
  #pragma unroll
  for (int j = 0; j < 8; j++) s += v[j];
  s = wredsum(s);
  float mean = s * (1.f/512.f);
  float q = 0.f;
  #pragma unroll
  for (int j = 0; j < 8; j++){ float t = v[j] - mean; q += t*t; }
  q = wredsum(q);
  float rstd = rsqrtf(q * (1.f/512.f) + 1e-5f);
  ushort hu[8], lu[8];
  #pragma unroll
  for (int j = 0; j < 8; j++){
    float h = (v[j] - mean) * rstd * g[d+j] + b[d+j];
    ushort hi = f2bf(h);
    hu[j] = hi;
    lu[j] = f2bf(h - bf2f(hi));
  }
  uint4 oh, ol;
  oh.x = (uint)hu[0] | ((uint)hu[1]<<16); oh.y = (uint)hu[2] | ((uint)hu[3]<<16);
  oh.z = (uint)hu[4] | ((uint)hu[5]<<16); oh.w = (uint)hu[6] | ((uint)hu[7]<<16);
  ol.x = (uint)lu[0] | ((uint)lu[1]<<16); ol.y = (uint)lu[2] | ((uint)lu[3]<<16);
  ol.z = (uint)lu[4] | ((uint)lu[5]<<16); ol.w = (uint)lu[6] | ((uint)lu[7]<<16);
  *(uint4*)(hhi + (size_t)row*512 + d) = oh;
  *(uint4*)(hlo + (size_t)row*512 + d) = ol;
}

// ---------- split GEMM (QKV / proj): C[M,N] = A[M,K] * Bt[N,K]^T, 128x128, BK=32 ----------
// EP: 0 = store f32 (qkv)   1 = +bias[col]+resid -> f32 (proj)
template<int EP>
__global__ __launch_bounds__(256) void gemm_bt(
    const ushort* __restrict__ A, const ushort* __restrict__ Alo,
    const ushort* __restrict__ B, const ushort* __restrict__ Blo,
    int M, int N, int K,
    float* __restrict__ outF,
    const float* __restrict__ bias, const float* __restrict__ resid)
{
  __shared__ __align__(16) ushort As[2][128*32];
  __shared__ __align__(16) ushort Bs[2][128*32];
  const int tid  = threadIdx.x;
  const int lane = tid & 63;
  const int w    = tid >> 6;
  const int wm   = w >> 1, wn = w & 1;
  const int bm   = blockIdx.x, bn = blockIdx.y;

  const int    srow = w*16 + (lane >> 2);
  const int    scol = (lane & 3) * 8;
  const size_t aoff = (size_t)(bm*128 + srow) * K + scol;
  const size_t boff = (size_t)(bn*128 + srow) * K + scol;
  const int lbase0 = (w*16) * 32;
  const int lbase1 = (64 + w*16) * 32;

  f32x4 acc[4][4];
  #pragma unroll
  for (int i = 0; i < 4; i++)
    #pragma unroll
    for (int j = 0; j < 4; j++) acc[i][j] = f32x4{0.f,0.f,0.f,0.f};

  const int nk = K >> 5;
  for (int kt = 0; kt < nk; ++kt) {
    const size_t ko = (size_t)kt * 32;
    gload16(A + aoff + ko,               &As[0][lbase0]);
    gload16(A + aoff + (size_t)64*K + ko,&As[0][lbase1]);
    gload16(B + boff + ko,               &Bs[0][lbase0]);
    gload16(B + boff + (size_t)64*K + ko,&Bs[0][lbase1]);
    gload16(Alo + aoff + ko,               &As[1][lbase0]);
    gload16(Alo + aoff + (size_t)64*K + ko,&As[1][lbase1]);
    gload16(Blo + boff + ko,               &Bs[1][lbase0]);
    gload16(Blo + boff + (size_t)64*K + ko,&Bs[1][lbase1]);
    __syncthreads();

    bf16x8 ah[4], bh[4], al[4], bl[4];
    const int kk = (lane >> 4) * 8;
    const int ar = wm*64 + (lane & 15);
    const int br = wn*64 + (lane & 15);
    #pragma unroll
    for (int i = 0; i < 4; i++){
      ah[i] = *(const bf16x8*)&As[0][(ar + i*16)*32 + kk];
      bh[i] = *(const bf16x8*)&Bs[0][(br + i*16)*32 + kk];
      al[i] = *(const bf16x8*)&As[1][(ar + i*16)*32 + kk];
      bl[i] = *(const bf16x8*)&Bs[1][(br + i*16)*32 + kk];
    }
    #pragma unroll
    for (int i = 0; i < 4; i++)
      #pragma unroll
      for (int j = 0; j < 4; j++){
        acc[i][j] = __builtin_amdgcn_mfma_f32_16x16x32_bf16(ah[i], bh[j], acc[i][j], 0,0,0);
        acc[i][j] = __builtin_amdgcn_mfma_f32_16x16x32_bf16(ah[i], bl[j], acc[i][j], 0,0,0);
        acc[i][j] = __builtin_amdgcn_mfma_f32_16x16x32_bf16(al[i], bh[j], acc[i][j], 0,0,0);
      }
    __syncthreads();
  }

  const int r0 = bm*128 + wm*64;
  const int c0 = bn*128 + wn*64;
  const int cl = lane & 15;
  const int rl = (lane >> 4) * 4;
  #pragma unroll
  for (int i = 0; i < 4; i++){
    #pragma unroll
    for (int r = 0; r < 4; r++){
      const int row = r0 + i*16 + rl + r;
      #pragma unroll
      for (int j = 0; j < 4; j++){
        const int col = c0 + j*16 + cl;
        float v = acc[i][j][r];
        size_t idx = (size_t)row * N + col;
        if constexpr (EP == 0) outF[idx] = v;
        else                   outF[idx] = v + bias[col] + resid[idx];
      }
    }
  }
}

// ---------- w1 (merged experts): single-buffer BK=64, swizzled, LDS-repack epilogue ----------
// gather A rows (h2) via list, gelu(acc+bias) -> mid slots (bf16), coalesced 16B stores
__global__ __launch_bounds__(256) void gemm_w1(
    const ushort* __restrict__ A, const ushort* __restrict__ Ball,
    const float* __restrict__ biasAll, ushort* __restrict__ midOut,
    const int* __restrict__ list, const int* __restrict__ seg)
{
  constexpr int K = 512, N = 2048, NBN = 16;
  // LB: staging (As @0, Bs @8192) aliased by repack tile T[128][132]
  __shared__ __align__(16) ushort LB[128*132];
  const int tid = threadIdx.x, lane = tid & 63, w = tid >> 6;
  const int wm = w >> 1, wn = w & 1;

  const int nloc = gridDim.x >> 3;
  const int lid  = (blockIdx.x & 7) * nloc + (blockIdx.x >> 3);
  const int bm   = lid / NBN, bn = lid % NBN;
  if (bm >= seg[4]) return;
  int e = 0;
  while (bm >= seg[e+1]) e++;
  const int ltile = bm - seg[e];
  const int* listE = list + e*16384;

  const int jrows = w * 32;
  const int lrow  = lane >> 3;
  const int lgcol = (((lane & 7) ^ lrow)) * 8;     // pre-swizzled source granule

  size_t asrc[4], bsrc[4];
  const ushort* Bm = Ball + (size_t)e * N * K;
  #pragma unroll
  for (int j = 0; j < 4; j++){
    int ar8 = jrows + j*8 + lrow;
    int tok = listE[ltile*128 + ar8];
    asrc[j] = (size_t)tok * K + lgcol;
    bsrc[j] = (size_t)(bn*128 + ar8) * K + lgcol;
  }

  f32x4 acc[4][4];
  #pragma unroll
  for (int i = 0; i < 4; i++)
    #pragma unroll
    for (int j = 0; j < 4; j++) acc[i][j] = f32x4{0.f,0.f,0.f,0.f};

  const int ar = wm*64 + (lane & 15);
  const int br = wn*64 + (lane & 15);
  const int rsw = lane & 7;

  #pragma unroll
  for (int kt = 0; kt < (K >> 6); ++kt){
    const size_t k0 = (size_t)kt * 64;
    #pragma unroll
    for (int j = 0; j < 4; j++){
      gload16(A  + asrc[j] + k0, &LB[(jrows + j*8)*64]);
      gload16(Bm + bsrc[j] + k0, &LB[8192 + (jrows + j*8)*64]);
    }
    __syncthreads();
    #pragma unroll
    for (int ks = 0; ks < 2; ++ks){
      const int g    = ks*4 + (lane >> 4);
      const int goff = (g ^ rsw) * 8;
      bf16x8 af[4], bfr[4];
      #pragma unroll
      for (int i = 0; i < 4; i++){
        af[i]  = *(const bf16x8*)&LB[(ar + i*16)*64 + goff];
        bfr[i] = *(const bf16x8*)&LB[8192 + (br + i*16)*64 + goff];
      }
      #pragma unroll
      for (int i = 0; i < 4; i++)
        #pragma unroll
        for (int j = 0; j < 4; j++)
          acc[i][j] = __builtin_amdgcn_mfma_f32_16x16x32_bf16(af[i], bfr[j], acc[i][j], 0,0,0);
    }
    __syncthreads();
  }

  // epilogue: gelu -> LDS repack tile [128][132] -> coalesced 16B stores
  const int cl = lane & 15;
  const int rl = (lane >> 4) * 4;
  float bj[4];
  #pragma unroll
  for (int j = 0; j < 4; j++)
    bj[j] = biasAll[e*N + bn*128 + wn*64 + j*16 + cl];
  #pragma unroll
  for (int i = 0; i < 4; i++){
    #pragma unroll
    for (int j = 0; j < 4; j++){
      const int cc = wn*64 + j*16 + cl;
      #pragma unroll
      for (int r = 0; r < 4; r++){
        const int rloc = wm*64 + i*16 + rl + r;
        float t = acc[i][j][r] + bj[j];
        float u2 = 1.5957691216057308f * (t + 0.044715f * t*t*t);
        float ex = __expf(u2);
        float gl = t - t * __builtin_amdgcn_rcpf(ex + 1.f);  // ex=inf -> t; ex->0 -> 0
        LB[rloc*132 + cc] = f2bf(gl);
      }
    }
  }
  __syncthreads();
  const int ch = tid & 15;
  #pragma unroll
  for (int it = 0; it < 8; ++it){
    const int rr = (tid >> 4) + it*16;
    bf16x8 v = *(const bf16x8*)&LB[rr*132 + ch*8];
    *(bf16x8*)&midOut[(size_t)(bm*128 + rr)*2048 + bn*128 + ch*8] = v;
  }
}

// ---------- w2 (merged experts): single-buffer BK=64, swizzled, LDS-repack epilogue ----------
// eout[slot] = mid[slot] @ w2[e]^T + b2[e]  (bf16, coalesced stores); 33 KB LDS -> 4 blocks/CU
__global__ __launch_bounds__(256) void gemm_w2(
    const ushort* __restrict__ mid, const ushort* __restrict__ Ball,
    const float* __restrict__ biasAll, ushort* __restrict__ eout,
    const int* __restrict__ seg)
{
  constexpr int K = 2048, N = 512, NBN = 4;
  __shared__ __align__(16) ushort LB[128*132];
  const int tid = threadIdx.x, lane = tid & 63, w = tid >> 6;
  const int wm = w >> 1, wn = w & 1;

  const int nloc = gridDim.x >> 3;
  const int lid  = (blockIdx.x & 7) * nloc + (blockIdx.x >> 3);
  const int bm   = lid / NBN, bn = lid % NBN;
  if (bm >= seg[4]) return;
  int e = 0;
  while (bm >= seg[e+1]) e++;

  const int jrows = w * 32;
  const int lrow  = lane >> 3;
  const int lgcol = (((lane & 7) ^ lrow)) * 8;

  size_t asrc[4], bsrc[4];
  const ushort* Bm = Ball + (size_t)e * N * K;
  #pragma unroll
  for (int j = 0; j < 4; j++){
    int ar8 = jrows + j*8 + lrow;
    asrc[j] = (size_t)(bm*128 + ar8) * K + lgcol;
    bsrc[j] = (size_t)(bn*128 + ar8) * K + lgcol;
  }

  f32x4 acc[4][4];
  #pragma unroll
  for (int i = 0; i < 4; i++)
    #pragma unroll
    for (int j = 0; j < 4; j++) acc[i][j] = f32x4{0.f,0.f,0.f,0.f};

  const int ar = wm*64 + (lane & 15);
  const int br = wn*64 + (lane & 15);
  const int rsw = lane & 7;

  for (int kt = 0; kt < (K >> 6); ++kt){
    const size_t k0 = (size_t)kt * 64;
    #pragma unroll
    for (int j = 0; j < 4; j++){
      gload16(mid + asrc[j] + k0, &LB[(jrows + j*8)*64]);
      gload16(Bm  + bsrc[j] + k0, &LB[8192 + (jrows + j*8)*64]);
    }
    __syncthreads();
    #pragma unroll
    for (int ks = 0; ks < 2; ++ks){
      const int g    = ks*4 + (lane >> 4);
      const int goff = (g ^ rsw) * 8;
      bf16x8 af[4], bfr[4];
      #pragma unroll
      for (int i = 0; i < 4; i++){
        af[i]  = *(const bf16x8*)&LB[(ar + i*16)*64 + goff];
        bfr[i] = *(const bf16x8*)&LB[8192 + (br + i*16)*64 + goff];
      }
      #pragma unroll
      for (int i = 0; i < 4; i++)
        #pragma unroll
        for (int j = 0; j < 4; j++)
          acc[i][j] = __builtin_amdgcn_mfma_f32_16x16x32_bf16(af[i], bfr[j], acc[i][j], 0,0,0);
    }
    __syncthreads();
  }

  // epilogue: +bias -> LDS repack [128][132] -> coalesced 16B stores
  const int cl = lane & 15;
  const int rl = (lane >> 4) * 4;
  float bj[4];
  #pragma unroll
  for (int j = 0; j < 4; j++)
    bj[j] = biasAll[e*N + bn*128 + wn*64 + j*16 + cl];
  #pragma unroll
  for (int i = 0; i < 4; i++){
    #pragma unroll
    for (int j = 0; j < 4; j++){
      const int cc = wn*64 + j*16 + cl;
      #pragma unroll
      for (int r = 0; r < 4; r++){
        const int rloc = wm*64 + i*16 + rl + r;
        LB[rloc*132 + cc] = f2bf(acc[i][j][r] + bj[j]);
      }
    }
  }
  __syncthreads();
  const int ch = tid & 15;
  #pragma unroll
  for (int it = 0; it < 8; ++it){
    const int rr = (tid >> 4) + it*16;
    bf16x8 v = *(const bf16x8*)&LB[rr*132 + ch*8];
    *(bf16x8*)&eout[(size_t)(bm*128 + rr)*512 + bn*128 + ch*8] = v;
  }
}

// ---------- combine: out[row] += w0*eout[gs0] + w1*eout[gs1] ----------
__global__ __launch_bounds__(256) void moe_combine(
    const ushort* __restrict__ eout, const int2* __restrict__ rowSlots,
    const float2* __restrict__ wts, float* __restrict__ out)
{
  int w = threadIdx.x >> 6, lane = threadIdx.x & 63;
  int row = blockIdx.x * 4 + w;
  int2 rs = rowSlots[row];
  float2 wv = wts[row];
  int d = lane * 8;
  uint4 u0 = *(const uint4*)(eout + (size_t)rs.x*512 + d);
  uint4 u1 = *(const uint4*)(eout + (size_t)rs.y*512 + d);
  float* op = out + (size_t)row*512 + d;
  float4 o0 = *(float4*)op;
  float4 o1 = *(float4*)(op + 4);
  o0.x += wv.x*bf2f((ushort)u0.x)        + wv.y*bf2f((ushort)u1.x);
  o0.y += wv.x*bf2f((ushort)(u0.x>>16))  + wv.y*bf2f((ushort)(u1.x>>16));
  o0.z += wv.x*bf2f((ushort)u0.y)        + wv.y*bf2f((ushort)u1.y);
  o0.w += wv.x*bf2f((ushort)(u0.y>>16))  + wv.y*bf2f((ushort)(u1.y>>16));
  o1.x += wv.x*bf2f((ushort)u0.z)        + wv.y*bf2f((ushort)u1.z);
  o1.y += wv.x*bf2f((ushort)(u0.z>>16))  + wv.y*bf2f((ushort)(u1.z>>16));
  o1.z += wv.x*bf2f((ushort)u0.w)        + wv.y*bf2f((ushort)u1.w);
  o1.w += wv.x*bf2f((ushort)(u0.w>>16))  + wv.y*bf2f((ushort)(u1.w>>16));
  *(float4*)op       = o0;
  *(float4*)(op + 4) = o1;
}

// ---------- attention: one wave per (b,h); qkv f32 [N,1536]; out att split bf16 [N,512] ----------
__global__ __launch_bounds__(64) void attn32(
    const float* __restrict__ qkv, ushort* __restrict__ atthi, ushort* __restrict__ attlo)
{
  int bh = blockIdx.x; int b = bh >> 4, h = bh & 15;
  __shared__ float qs[32][33], ks[32][33], vs[32][33], ps[32][33];
  int lane = threadIdx.x;
  int t = lane >> 1, cb = (lane & 1) * 16;
  const float* src = qkv + (size_t)(b*32 + t)*1536 + h*32 + cb;
  #pragma unroll
  for (int j = 0; j < 16; j += 4){
    float4 q4 = *(const float4*)(src + j);
    float4 k4 = *(const float4*)(src + 512 + j);
    float4 v4 = *(const float4*)(src + 1024 + j);
    qs[t][cb+j]=q4.x; qs[t][cb+j+1]=q4.y; qs[t][cb+j+2]=q4.z; qs[t][cb+j+3]=q4.w;
    ks[t][cb+j]=k4.x; ks[t][cb+j+1]=k4.y; ks[t][cb+j+2]=k4.z; ks[t][cb+j+3]=k4.w;
    vs[t][cb+j]=v4.x; vs[t][cb+j+1]=v4.y; vs[t][cb+j+2]=v4.z; vs[t][cb+j+3]=v4.w;
  }
  __syncthreads();
  const float scale = 0.044194173824159216f; // 1/sqrt(512)
  float sc[16];
  #pragma unroll
  for (int j = 0; j < 16; j++){
    int c = cb + j;
    if (c <= t) {
      float d = 0.f;
      #pragma unroll
      for (int i = 0; i < 32; i++) d += qs[t][i] * ks[c][i];
      sc[j] = d * scale;
    } else sc[j] = -1e30f;
  }
  float mx = -1e30f;
  #pragma unroll
  for (int j = 0; j < 16; j++) mx = fmaxf(mx, sc[j]);
  mx = fmaxf(mx, __shfl_xor(mx, 1));
  float p[16], sum = 0.f;
  #pragma unroll
  for (int j = 0; j < 16; j++){
    int c = cb + j;
    if (c <= t) { p[j] = expf(sc[j] - mx); sum += p[j]; } else p[j] = 0.f;
  }
  sum += __shfl_xor(sum, 1);
  float inv = 1.f / sum;
  #pragma unroll
  for (int j = 0; j < 16; j++) ps[t][cb+j] = p[j] * inv;
  __syncthreads();
  float o[16];
  #pragma unroll
  for (int j = 0; j < 16; j++) o[j] = 0.f;
  for (int s2 = 0; s2 <= t; ++s2){
    float wv = ps[t][s2];
    #pragma unroll
    for (int j = 0; j < 16; j++) o[j] += wv * vs[s2][cb+j];
  }
  size_t base = (size_t)(b*32 + t)*512 + h*32 + cb;
  ushort hu[16], lu[16];
  #pragma unroll
  for (int j = 0; j < 16; j++){
    ushort hi = f2bf(o[j]);
    hu[j] = hi; lu[j] = f2bf(o[j] - bf2f(hi));
  }
  uint4 oh0, oh1, ol0, ol1;
  oh0.x=(uint)hu[0]|((uint)hu[1]<<16);  oh0.y=(uint)hu[2]|((uint)hu[3]<<16);
  oh0.z=(uint)hu[4]|((uint)hu[5]<<16);  oh0.w=(uint)hu[6]|((uint)hu[7]<<16);
  oh1.x=(uint)hu[8]|((uint)hu[9]<<16);  oh1.y=(uint)hu[10]|((uint)hu[11]<<16);
  oh1.z=(uint)hu[12]|((uint)hu[13]<<16);oh1.w=(uint)hu[14]|((uint)hu[15]<<16);
  ol0.x=(uint)lu[0]|((uint)lu[1]<<16);  ol0.y=(uint)lu[2]|((uint)lu[3]<<16);
  ol0.z=(uint)lu[4]|((uint)lu[5]<<16);  ol0.w=(uint)lu[6]|((uint)lu[7]<<16);
  ol1.x=(uint)lu[8]|((uint)lu[9]<<16);  ol1.y=(uint)lu[10]|((uint)lu[11]<<16);
  ol1.z=(uint)lu[12]|((uint)lu[13]<<16);ol1.w=(uint)lu[14]|((uint)lu[15]<<16);
  *(uint4*)(atthi + base)     = oh0;  *(uint4*)(atthi + base + 8) = oh1;
  *(uint4*)(attlo + base)     = ol0;  *(uint4*)(attlo + base + 8) = ol1;
}

// ---------- LN2 + gate: NO atomics. Per-row selection + per-block expert counts ----------
__global__ __launch_bounds__(256) void ln2_gate(
    const float* __restrict__ x1, const float* __restrict__ g, const float* __restrict__ b,
    const float* __restrict__ wgate, ushort* __restrict__ h2,
    int* __restrict__ selp, float2* __restrict__ wts,
    int* __restrict__ blockCnt, float* __restrict__ partials)
{
  __shared__ float wsumLds[4];
  __shared__ int   selLds[4];
  int w = threadIdx.x >> 6, lane = threadIdx.x & 63;
  int row = blockIdx.x * 4 + w;
  const float* xr = x1 + (size_t)row * 512;
  int d = lane * 8;
  float4 a0 = *(const float4*)(xr + d);
  float4 a1 = *(const float4*)(xr + d + 4);
  float v[8] = {a0.x,a0.y,a0.z,a0.w,a1.x,a1.y,a1.z,a1.w};
  float s = 0.f;
  #pragma unroll
  for (int j = 0; j < 8; j++) s += v[j];
  s = wredsum(s);
  float mean = s * (1.f/512.f);
  float q = 0.f;
  #pragma unroll
  for (int j = 0; j < 8; j++){ float t = v[j] - mean; q += t*t; }
  q = wredsum(q);
  float rstd = rsqrtf(q * (1.f/512.f) + 1e-5f);
  float acc0=0.f, acc1=0.f, acc2=0.f, acc3=0.f;
  ushort hu[8];
  #pragma unroll
  for (int j = 0; j < 8; j++){
    float h = (v[j] - mean) * rstd * g[d+j] + b[d+j];
    hu[j] = f2bf(h);
    float4 wgv = *(const float4*)(wgate + (size_t)(d+j)*4);
    acc0 += h * wgv.x; acc1 += h * wgv.y; acc2 += h * wgv.z; acc3 += h * wgv.w;
  }
  uint4 oh;
  oh.x=(uint)hu[0]|((uint)hu[1]<<16); oh.y=(uint)hu[2]|((uint)hu[3]<<16);
  oh.z=(uint)hu[4]|((uint)hu[5]<<16); oh.w=(uint)hu[6]|((uint)hu[7]<<16);
  *(uint4*)(h2 + (size_t)row*512 + d) = oh;
  acc0 = wredsum(acc0); acc1 = wredsum(acc1); acc2 = wredsum(acc2); acc3 = wredsum(acc3);
  if (lane == 0){
    float l[4] = {acc0, acc1, acc2, acc3};
    int i0 = 0;
    for (int e = 1; e < 4; e++) if (l[e] > l[i0]) i0 = e;
    int i1 = -1;
    for (int e = 0; e < 4; e++){ if (e == i0) continue; if (i1 < 0 || l[e] > l[i1]) i1 = e; }
    float e1 = expf(l[i1] - l[i0]);
    float w1v = e1 / (1.f + e1), w0v = 1.f / (1.f + e1);
    int packed = i0 | (i1 << 8);
    selp[row] = packed;
    wts[row]  = make_float2(w0v, w1v);
    selLds[w] = packed;
    wsumLds[w] = l[0] + l[1] + l[2] + l[3];
  }
  __syncthreads();
  if (threadIdx.x < 4){
    int e = threadIdx.x, c = 0;
    #pragma unroll
    for (int i = 0; i < 4; i++){
      int sp = selLds[i];
      c += ((sp & 0xff) == e) + (((sp >> 8) & 0xff) == e);
    }
    blockCnt[e*4096 + blockIdx.x] = c;
  }
  if (threadIdx.x == 0)
    partials[blockIdx.x] = wsumLds[0] + wsumLds[1] + wsumLds[2] + wsumLds[3];
}

// ---------- scan: per-expert block offsets + totals + segments + balance loss ----------
__global__ __launch_bounds__(256) void scan_offsets(
    const int* __restrict__ blockCnt, int* __restrict__ blockOff,
    int* __restrict__ cnt, int* __restrict__ seg,
    const float* __restrict__ partials, float* __restrict__ lossOut)
{
  __shared__ int cntL[4];
  __shared__ float ws4[4];
  int w = threadIdx.x >> 6, lane = threadIdx.x & 63;
  const int* src = blockCnt + w*4096;
  int* dst = blockOff + w*4096;
  int off = 0;
  for (int i = 0; i < 4096; i += 64){
    int v = src[i + lane];
    int orig = v;
    #pragma unroll
    for (int dlt = 1; dlt < 64; dlt <<= 1){
      int t = __shfl_up(v, dlt);
      if (lane >= dlt) v += t;
    }
    dst[i + lane] = off + v - orig;   // exclusive prefix
    off += __shfl(v, 63);
  }
  if (lane == 0){ cnt[w] = off; cntL[w] = off; }
  __syncthreads();
  if (threadIdx.x == 0){
    int t = 0;
    for (int e = 0; e < 4; e++){ seg[e] = t; t += (cntL[e] + 127) >> 7; }
    seg[4] = t;
  }
  // fused balance loss (was gate_reduce)
  float s = 0.f;
  for (int i = threadIdx.x; i < 4096; i += 256) s += partials[i];
  s = wredsum(s);
  if ((threadIdx.x & 63) == 0) ws4[threadIdx.x >> 6] = s;
  __syncthreads();
  if (threadIdx.x == 0){
    float tot = ws4[0] + ws4[1] + ws4[2] + ws4[3];
    float ep = tot * (1.f/65536.f);
    lossOut[0] = ep * logf(ep + 0.1f);
  }
}

// ---------- write compacted routing lists + per-row global slots (deterministic) ----------
__global__ __launch_bounds__(256) void route_write(
    const int* __restrict__ selp, const int* __restrict__ blockOff,
    const int* __restrict__ seg, int* __restrict__ list, int2* __restrict__ rowSlots)
{
  int row = blockIdx.x * 256 + threadIdx.x;
  int g = row & ~3;          // base row of the ln2_gate block (4 rows/block)
  int b = row >> 2;          // ln2_gate block index
  int my = selp[row];
  int e0 = my & 0xff, e1 = (my >> 8) & 0xff;
  int r0 = 0, r1 = 0;
  for (int r = g; r < row; ++r){
    int sp = selp[r];
    int a = sp & 0xff, c = (sp >> 8) & 0xff;
    r0 += (a == e0) + (c == e0);
    r1 += (a == e1) + (c == e1);
  }
  int slot0 = blockOff[e0*4096 + b] + r0;
  int slot1 = blockOff[e1*4096 + b] + r1;
  list[e0*16384 + slot0] = row;
  list[e1*16384 + slot1] = row;
  rowSlots[row] = make_int2(seg[e0]*128 + slot0, seg[e1]*128 + slot1);
}

// ---------- host ----------
extern "C" void kernel_launch(void* const* d_in, const int* in_sizes, int n_in,
                              void* d_out, int out_size, void* d_ws, size_t ws_size,
                              hipStream_t stream)
{
  const float* x     = (const float*)d_in[0];
  const float* ln1g  = (const float*)d_in[1];
  const float* ln1b  = (const float*)d_in[2];
  const float* wq    = (const float*)d_in[3];
  const float* wk    = (const float*)d_in[4];
  const float* wv    = (const float*)d_in[5];
  const float* wproj = (const float*)d_in[6];
  const float* bproj = (const float*)d_in[7];
  const float* ln2g  = (const float*)d_in[8];
  const float* ln2b  = (const float*)d_in[9];
  const float* wgate = (const float*)d_in[10];
  const float* w1    = (const float*)d_in[11];
  const float* b1    = (const float*)d_in[12];
  const float* w2    = (const float*)d_in[13];
  const float* b2    = (const float*)d_in[14];
  float* out = (float*)d_out;

  char* ws = (char*)d_ws;
  // ---- early arena (dead before MoE) ----
  ushort* hHi   = (ushort*)(ws + 0);              // [P0-P1]
  ushort* hLo   = (ushort*)(ws + 16777216);       // [P0-P1]
  ushort* qkvTh = (ushort*)(ws + 33554432);       // [P0-P1]
  ushort* qkvTl = (ushort*)(ws + 35127296);
  ushort* pTh   = (ushort*)(ws + 36700160);       // [P0-P3]
  ushort* pTl   = (ushort*)(ws + 37224448);
  float*  qkvF  = (float*)(ws + 37748736);        // [P1-P2], ends 138412032
  ushort* attHi = (ushort*)(ws + 138412032);      // [P2-P3]
  ushort* attLo = (ushort*)(ws + 155189248);      // [P2-P3], ends 171966464
  // ---- late arena (overlays early, time-disjoint) ----
  ushort* mid   = (ushort*)(ws + 0);              // 136.31 MB [w1-w2], ends 136314880
  ushort* eout  = (ushort*)(ws + 137183744);      // 34.08 MB  [w2-combine], ends 171262464
  // ---- persistent ----
  ushort* h2    = (ushort*)(ws + 171966464);      // [ln2-w1]
  ushort* w1T   = (ushort*)(ws + 188743680);      // [P0-w1]
  ushort* w2T   = (ushort*)(ws + 197132288);      // [P0-w2], ends 205520896
  // ---- routing block: qkvF tail carve [136314880, 137183744) ----
  char* rb = ws + 136314880;
  int*    cnt      = (int*)   (rb + 0);
  int*    seg      = (int*)   (rb + 256);
  int*    list     = (int*)   (rb + 512);         // 262144 B
  int2*   rowSlots = (int2*)  (rb + 262656);      // 131072 B
  float*  partials = (float*) (rb + 524800);      // 16384 B
  int*    selp     = (int*)   (rb + 541184);      // 65536 B
  float2* wts      = (float2*)(rb + 606720);      // 131072 B
  int*    blockCnt = (int*)   (rb + 737792);      // 65536 B
  int*    blockOff = (int*)   (rb + 803328);      // 65536 B -> ends 868864

  // weight prep (transpose + bf16 [split] conversion)
  transpose_qkv<<<dim3(1,16,48), 256, 0, stream>>>(wq, wk, wv, qkvTh, qkvTl);
  transpose_to_bf16<true ><<<dim3(16,16,1), 256, 0, stream>>>(wproj, pTh, pTl, 512, 512);
  transpose_to_bf16<false><<<dim3(64,16,4), 256, 0, stream>>>(w1, w1T, nullptr, 512, 2048);
  transpose_to_bf16<false><<<dim3(16,64,4), 256, 0, stream>>>(w2, w2T, nullptr, 2048, 512);

  // LN1 (split precision)
  ln_split<<<dim3(4096), 256, 0, stream>>>(x, ln1g, ln1b, hHi, hLo);

  // QKV = h @ Wqkv (split-bf16, f32-grade) -> f32 [N,1536]
  gemm_bt<0><<<dim3(128,12), 256, 0, stream>>>(hHi, hLo, qkvTh, qkvTl,
      16384, 1536, 512, qkvF, nullptr, nullptr);

  // attention per (b,h)
  attn32<<<dim3(8192), 64, 0, stream>>>(qkvF, attHi, attLo);

  // x1 = x + att @ Wproj + b_proj (split-bf16) -> d_out f32
  gemm_bt<1><<<dim3(128,4), 256, 0, stream>>>(attHi, attLo, pTh, pTl,
      16384, 512, 512, out, bproj, x);

  // routing: LN2+gate (no atomics) -> scan(+loss) -> compacted lists + rowSlots
  (void)hipMemsetAsync(list, 0, 4*16384*sizeof(int), stream);  // pad slots gather row 0
  ln2_gate<<<dim3(4096), 256, 0, stream>>>(out, ln2g, ln2b, wgate, h2, selp, wts, blockCnt, partials);
  scan_offsets<<<dim3(1), 256, 0, stream>>>(blockCnt, blockOff, cnt, seg, partials, out + 8388608);
  route_write<<<dim3(64), 256, 0, stream>>>(selp, blockOff, seg, list, rowSlots);

  // MoE: merged w1 (gather+gelu -> mid), merged w2 (-> eout), deterministic combine
  gemm_w1<<<dim3(4160), 256, 0, stream>>>(h2,  w1T, b1, mid,  list, seg);
  gemm_w2<<<dim3(1040), 256, 0, stream>>>(mid, w2T, b2, eout, seg);
  moe_combine<<<dim3(4096), 256, 0, stream>>>(eout, rowSlots, wts, out);
}

// Round 10
// 463.813 us; speedup vs baseline: 1.0499x; 1.0499x over previous
//
#include <hip/hip_runtime.h>

typedef unsigned short ushort;
typedef unsigned int   uint;
typedef short bf16x8 __attribute__((ext_vector_type(8)));
typedef float f32x4  __attribute__((ext_vector_type(4)));

// ---------- helpers ----------
__device__ __forceinline__ float bf2f(ushort u){
  union { uint u; float f; } c; c.u = ((uint)u) << 16; return c.f;
}
__device__ __forceinline__ ushort f2bf(float f){
  union { float f; uint u; } c; c.f = f;
  return (ushort)((c.u + 0x7fffu + ((c.u >> 16) & 1u)) >> 16);
}
__device__ __forceinline__ float wredsum(float v){
  #pragma unroll
  for (int off = 32; off > 0; off >>= 1) v += __shfl_xor(v, off);
  return v;
}
__device__ __forceinline__ void gload16(const void* g, void* l){
  __builtin_amdgcn_global_load_lds((__attribute__((address_space(1))) void*)(void*)g,
                                   (__attribute__((address_space(3))) void*)l, 16, 0, 0);
}

// ---------- transpose f32 [R][C] -> bf16 [C][R] (optionally split hi/lo), per-z slice ----------
template<bool SPLIT>
__global__ __launch_bounds__(256) void transpose_to_bf16(
    const float* __restrict__ src, ushort* __restrict__ dhi, ushort* __restrict__ dlo,
    int R, int C)
{
  __shared__ float tile[32][33];
  size_t zoff = (size_t)blockIdx.z * R * C;
  src += zoff; dhi += zoff; if (SPLIT) dlo += zoff;
  int c0 = blockIdx.x * 32, r0 = blockIdx.y * 32;
  int tx = threadIdx.x & 31, ty = threadIdx.x >> 5;
  #pragma unroll
  for (int i = 0; i < 32; i += 8)
    tile[ty + i][tx] = src[(size_t)(r0 + ty + i) * C + (c0 + tx)];
  __syncthreads();
  #pragma unroll
  for (int i = 0; i < 32; i += 8){
    float v = tile[tx][ty + i];
    ushort hi = f2bf(v);
    dhi[(size_t)(c0 + ty + i) * R + (r0 + tx)] = hi;
    if constexpr (SPLIT)
      dlo[(size_t)(c0 + ty + i) * R + (r0 + tx)] = f2bf(v - bf2f(hi));
  }
}

// ---------- fused q/k/v weight transpose: [512,32] x16 heads x3 tensors -> split bf16 ----------
__global__ __launch_bounds__(256) void transpose_qkv(
    const float* __restrict__ wq, const float* __restrict__ wk, const float* __restrict__ wv,
    ushort* __restrict__ dhi, ushort* __restrict__ dlo)
{
  __shared__ float tile[32][33];
  int z = blockIdx.z;                 // 0..47
  int which = z >> 4, h = z & 15;
  const float* src = (which == 0) ? wq : (which == 1) ? wk : wv;
  size_t soff = (size_t)h * 512 * 32;
  size_t doff = (size_t)which * 262144 + soff;
  src += soff;
  int r0 = blockIdx.y * 32;
  int tx = threadIdx.x & 31, ty = threadIdx.x >> 5;
  #pragma unroll
  for (int i = 0; i < 32; i += 8)
    tile[ty + i][tx] = src[(size_t)(r0 + ty + i) * 32 + tx];
  __syncthreads();
  #pragma unroll
  for (int i = 0; i < 32; i += 8){
    float v = tile[tx][ty + i];
    ushort hi = f2bf(v);
    dhi[doff + (size_t)(ty + i) * 512 + (r0 + tx)] = hi;
    dlo[doff + (size_t)(ty + i) * 512 + (r0 + tx)] = f2bf(v - bf2f(hi));
  }
}

// ---------- LN1: x[N,512] f32 -> h split bf16 hi/lo ----------
__global__ __launch_bounds__(256) void ln_split(
    const float* __restrict__ x, const float* __restrict__ g, const float* __restrict__ b,
    ushort* __restrict__ hhi, ushort* __restrict__ hlo)
{
  int w = threadIdx.x >> 6, lane = threadIdx.x & 63;
  int row = blockIdx.x * 4 + w;
  const float* xr = x + (size_t)row * 512;
  int d = lane * 8;
  float4 a0 = *(const float4*)(xr + d);
  float4 a1 = *(const float4*)(xr + d + 4);
  float v[8] = {a0.x,a0.y,a0.z,a0.w,a1.x,a1.y,a1.z,a1.w};
  float s = 0.f;
  #pragma unroll
  for (int j = 0; j < 8; j++) s += v[j];
  s = wredsum(s);
  float mean = s * (1.f/512.f);
  float q = 0.f;
  #pragma unroll
  for (int j = 0; j < 8; j++){ float t = v[j] - mean; q += t*t; }
  q = wredsum(q);
  float rstd = rsqrtf(q * (1.f/512.f) + 1e-5f);
  ushort hu[8], lu[8];
  #pragma unroll
  for (int j = 0; j < 8; j++){
    float h = (v[j] - mean) * rstd * g[d+j] + b[d+j];
    ushort hi = f2bf(h);
    hu[j] = hi;
    lu[j] = f2bf(h - bf2f(hi));
  }
  uint4 oh, ol;
  oh.x = (uint)hu[0] | ((uint)hu[1]<<16); oh.y = (uint)hu[2] | ((uint)hu[3]<<16);
  oh.z = (uint)hu[4] | ((uint)hu[5]<<16); oh.w = (uint)hu[6] | ((uint)hu[7]<<16);
  ol.x = (uint)lu[0] | ((uint)lu[1]<<16); ol.y = (uint)lu[2] | ((uint)lu[3]<<16);
  ol.z = (uint)lu[4] | ((uint)lu[5]<<16); ol.w = (uint)lu[6] | ((uint)lu[7]<<16);
  *(uint4*)(hhi + (size_t)row*512 + d) = oh;
  *(uint4*)(hlo + (size_t)row*512 + d) = ol;
}

// ---------- split GEMM (QKV / proj): C[M,N] = A[M,K] * Bt[N,K]^T, 128x128, BK=32 ----------
// EP: 0 = store f32 (qkv)   1 = +bias[col]+resid -> f32 (proj)
template<int EP>
__global__ __launch_bounds__(256) void gemm_bt(
    const ushort* __restrict__ A, const ushort* __restrict__ Alo,
    const ushort* __restrict__ B, const ushort* __restrict__ Blo,
    int M, int N, int K,
    float* __restrict__ outF,
    const float* __restrict__ bias, const float* __restrict__ resid)
{
  __shared__ __align__(16) ushort As[2][128*32];
  __shared__ __align__(16) ushort Bs[2][128*32];
  const int tid  = threadIdx.x;
  const int lane = tid & 63;
  const int w    = tid >> 6;
  const int wm   = w >> 1, wn = w & 1;
  const int bm   = blockIdx.x, bn = blockIdx.y;

  const int    srow = w*16 + (lane >> 2);
  const int    scol = (lane & 3) * 8;
  const size_t aoff = (size_t)(bm*128 + srow) * K + scol;
  const size_t boff = (size_t)(bn*128 + srow) * K + scol;
  const int lbase0 = (w*16) * 32;
  const int lbase1 = (64 + w*16) * 32;

  f32x4 acc[4][4];
  #pragma unroll
  for (int i = 0; i < 4; i++)
    #pragma unroll
    for (int j = 0; j < 4; j++) acc[i][j] = f32x4{0.f,0.f,0.f,0.f};

  const int nk = K >> 5;
  for (int kt = 0; kt < nk; ++kt) {
    const size_t ko = (size_t)kt * 32;
    gload16(A + aoff + ko,               &As[0][lbase0]);
    gload16(A + aoff + (size_t)64*K + ko,&As[0][lbase1]);
    gload16(B + boff + ko,               &Bs[0][lbase0]);
    gload16(B + boff + (size_t)64*K + ko,&Bs[0][lbase1]);
    gload16(Alo + aoff + ko,               &As[1][lbase0]);
    gload16(Alo + aoff + (size_t)64*K + ko,&As[1][lbase1]);
    gload16(Blo + boff + ko,               &Bs[1][lbase0]);
    gload16(Blo + boff + (size_t)64*K + ko,&Bs[1][lbase1]);
    __syncthreads();

    bf16x8 ah[4], bh[4], al[4], bl[4];
    const int kk = (lane >> 4) * 8;
    const int ar = wm*64 + (lane & 15);
    const int br = wn*64 + (lane & 15);
    #pragma unroll
    for (int i = 0; i < 4; i++){
      ah[i] = *(const bf16x8*)&As[0][(ar + i*16)*32 + kk];
      bh[i] = *(const bf16x8*)&Bs[0][(br + i*16)*32 + kk];
      al[i] = *(const bf16x8*)&As[1][(ar + i*16)*32 + kk];
      bl[i] = *(const bf16x8*)&Bs[1][(br + i*16)*32 + kk];
    }
    #pragma unroll
    for (int i = 0; i < 4; i++)
      #pragma unroll
      for (int j = 0; j < 4; j++){
        acc[i][j] = __builtin_amdgcn_mfma_f32_16x16x32_bf16(ah[i], bh[j], acc[i][j], 0,0,0);
        acc[i][j] = __builtin_amdgcn_mfma_f32_16x16x32_bf16(ah[i], bl[j], acc[i][j], 0,0,0);
        acc[i][j] = __builtin_amdgcn_mfma_f32_16x16x32_bf16(al[i], bh[j], acc[i][j], 0,0,0);
      }
    __syncthreads();
  }

  const int r0 = bm*128 + wm*64;
  const int c0 = bn*128 + wn*64;
  const int cl = lane & 15;
  const int rl = (lane >> 4) * 4;
  #pragma unroll
  for (int i = 0; i < 4; i++){
    #pragma unroll
    for (int r = 0; r < 4; r++){
      const int row = r0 + i*16 + rl + r;
      #pragma unroll
      for (int j = 0; j < 4; j++){
        const int col = c0 + j*16 + cl;
        float v = acc[i][j][r];
        size_t idx = (size_t)row * N + col;
        if constexpr (EP == 0) outF[idx] = v;
        else                   outF[idx] = v + bias[col] + resid[idx];
      }
    }
  }
}

// ---------- w1 (merged experts): single-buffer BK=64, swizzled, LDS-repack epilogue ----------
// gather A rows (h2) via list, gelu(acc+bias) -> mid slots (bf16), coalesced 16B stores
__global__ __launch_bounds__(256) void gemm_w1(
    const ushort* __restrict__ A, const ushort* __restrict__ Ball,
    const float* __restrict__ biasAll, ushort* __restrict__ midOut,
    const int* __restrict__ list, const int* __restrict__ seg)
{
  constexpr int K = 512, N = 2048, NBN = 16;
  // LB: staging (As @0, Bs @8192) aliased by repack tile T[128][132]
  __shared__ __align__(16) ushort LB[128*132];
  const int tid = threadIdx.x, lane = tid & 63, w = tid >> 6;
  const int wm = w >> 1, wn = w & 1;

  const int nloc = gridDim.x >> 3;
  const int lid  = (blockIdx.x & 7) * nloc + (blockIdx.x >> 3);
  const int bm   = lid / NBN, bn = lid % NBN;
  if (bm >= seg[4]) return;
  int e = 0;
  while (bm >= seg[e+1]) e++;
  const int ltile = bm - seg[e];
  const int* listE = list + e*16384;

  const int jrows = w * 32;
  const int lrow  = lane >> 3;
  const int lgcol = (((lane & 7) ^ lrow)) * 8;     // pre-swizzled source granule

  size_t asrc[4], bsrc[4];
  const ushort* Bm = Ball + (size_t)e * N * K;
  #pragma unroll
  for (int j = 0; j < 4; j++){
    int ar8 = jrows + j*8 + lrow;
    int tok = listE[ltile*128 + ar8];
    asrc[j] = (size_t)tok * K + lgcol;
    bsrc[j] = (size_t)(bn*128 + ar8) * K + lgcol;
  }

  f32x4 acc[4][4];
  #pragma unroll
  for (int i = 0; i < 4; i++)
    #pragma unroll
    for (int j = 0; j < 4; j++) acc[i][j] = f32x4{0.f,0.f,0.f,0.f};

  const int ar = wm*64 + (lane & 15);
  const int br = wn*64 + (lane & 15);
  const int rsw = lane & 7;

  #pragma unroll
  for (int kt = 0; kt < (K >> 6); ++kt){
    const size_t k0 = (size_t)kt * 64;
    #pragma unroll
    for (int j = 0; j < 4; j++){
      gload16(A  + asrc[j] + k0, &LB[(jrows + j*8)*64]);
      gload16(Bm + bsrc[j] + k0, &LB[8192 + (jrows + j*8)*64]);
    }
    __syncthreads();
    #pragma unroll
    for (int ks = 0; ks < 2; ++ks){
      const int g    = ks*4 + (lane >> 4);
      const int goff = (g ^ rsw) * 8;
      bf16x8 af[4], bfr[4];
      #pragma unroll
      for (int i = 0; i < 4; i++){
        af[i]  = *(const bf16x8*)&LB[(ar + i*16)*64 + goff];
        bfr[i] = *(const bf16x8*)&LB[8192 + (br + i*16)*64 + goff];
      }
      #pragma unroll
      for (int i = 0; i < 4; i++)
        #pragma unroll
        for (int j = 0; j < 4; j++)
          acc[i][j] = __builtin_amdgcn_mfma_f32_16x16x32_bf16(af[i], bfr[j], acc[i][j], 0,0,0);
    }
    __syncthreads();
  }

  // epilogue: gelu -> LDS repack tile [128][132] -> coalesced 16B stores
  const int cl = lane & 15;
  const int rl = (lane >> 4) * 4;
  float bj[4];
  #pragma unroll
  for (int j = 0; j < 4; j++)
    bj[j] = biasAll[e*N + bn*128 + wn*64 + j*16 + cl];
  #pragma unroll
  for (int i = 0; i < 4; i++){
    #pragma unroll
    for (int j = 0; j < 4; j++){
      const int cc = wn*64 + j*16 + cl;
      #pragma unroll
      for (int r = 0; r < 4; r++){
        const int rloc = wm*64 + i*16 + rl + r;
        float t = acc[i][j][r] + bj[j];
        float u2 = 1.5957691216057308f * (t + 0.044715f * t*t*t);
        float ex = __expf(u2);
        float gl = t - t * __builtin_amdgcn_rcpf(ex + 1.f);  // ex=inf -> t; ex->0 -> 0
        LB[rloc*132 + cc] = f2bf(gl);
      }
    }
  }
  __syncthreads();
  const int ch = tid & 15;
  #pragma unroll
  for (int it = 0; it < 8; ++it){
    const int rr = (tid >> 4) + it*16;
    bf16x8 v = *(const bf16x8*)&LB[rr*132 + ch*8];
    *(bf16x8*)&midOut[(size_t)(bm*128 + rr)*2048 + bn*128 + ch*8] = v;
  }
}

// ---------- w2 (merged experts): dbuf BK=64, swizzled, LDS-repack epilogue ----------
// eout[slot] = mid[slot] @ w2[e]^T + b2[e]  (bf16, coalesced stores)
// LB layout (ushorts): As0 @0, As1 @8192, Bs0 @16384, Bs1 @24576; repack aliases front
__global__ __launch_bounds__(256) void gemm_w2(
    const ushort* __restrict__ mid, const ushort* __restrict__ Ball,
    const float* __restrict__ biasAll, ushort* __restrict__ eout,
    const int* __restrict__ seg)
{
  constexpr int K = 2048, N = 512, NBN = 4;
  __shared__ __align__(16) ushort LB[4*128*64];
  const int tid = threadIdx.x, lane = tid & 63, w = tid >> 6;
  const int wm = w >> 1, wn = w & 1;

  const int nloc = gridDim.x >> 3;
  const int lid  = (blockIdx.x & 7) * nloc + (blockIdx.x >> 3);
  const int bm   = lid / NBN, bn = lid % NBN;
  if (bm >= seg[4]) return;
  int e = 0;
  while (bm >= seg[e+1]) e++;

  const int jrows = w * 32;
  const int lrow  = lane >> 3;
  const int lgcol = (((lane & 7) ^ lrow)) * 8;

  size_t asrc[4], bsrc[4];
  const ushort* Bm = Ball + (size_t)e * N * K;
  #pragma unroll
  for (int j = 0; j < 4; j++){
    int ar8 = jrows + j*8 + lrow;
    asrc[j] = (size_t)(bm*128 + ar8) * K + lgcol;
    bsrc[j] = (size_t)(bn*128 + ar8) * K + lgcol;
  }

  f32x4 acc[4][4];
  #pragma unroll
  for (int i = 0; i < 4; i++)
    #pragma unroll
    for (int j = 0; j < 4; j++) acc[i][j] = f32x4{0.f,0.f,0.f,0.f};

  constexpr int nk = K >> 6;

  #pragma unroll
  for (int j = 0; j < 4; j++){
    gload16(mid + asrc[j], &LB[(jrows + j*8)*64]);
    gload16(Bm  + bsrc[j], &LB[16384 + (jrows + j*8)*64]);
  }
  __syncthreads();

  const int ar = wm*64 + (lane & 15);
  const int br = wn*64 + (lane & 15);
  const int rsw = lane & 7;

  for (int kt = 0; kt < nk; ++kt){
    const int cur = kt & 1;
    const int curA = cur * 8192;
    const int nxtA = (cur ^ 1) * 8192;
    if (kt + 1 < nk){
      const size_t k0 = (size_t)(kt + 1) * 64;
      #pragma unroll
      for (int j = 0; j < 4; j++){
        gload16(mid + asrc[j] + k0, &LB[nxtA + (jrows + j*8)*64]);
        gload16(Bm  + bsrc[j] + k0, &LB[16384 + nxtA + (jrows + j*8)*64]);
      }
    }
    #pragma unroll
    for (int ks = 0; ks < 2; ++ks){
      const int g    = ks*4 + (lane >> 4);
      const int goff = (g ^ rsw) * 8;
      bf16x8 af[4], bfr[4];
      #pragma unroll
      for (int i = 0; i < 4; i++){
        af[i]  = *(const bf16x8*)&LB[curA + (ar + i*16)*64 + goff];
        bfr[i] = *(const bf16x8*)&LB[16384 + curA + (br + i*16)*64 + goff];
      }
      #pragma unroll
      for (int i = 0; i < 4; i++)
        #pragma unroll
        for (int j = 0; j < 4; j++)
          acc[i][j] = __builtin_amdgcn_mfma_f32_16x16x32_bf16(af[i], bfr[j], acc[i][j], 0,0,0);
    }
    __syncthreads();
  }

  // epilogue: +bias -> LDS repack [128][132] -> coalesced 16B stores
  const int cl = lane & 15;
  const int rl = (lane >> 4) * 4;
  float bj[4];
  #pragma unroll
  for (int j = 0; j < 4; j++)
    bj[j] = biasAll[e*N + bn*128 + wn*64 + j*16 + cl];
  #pragma unroll
  for (int i = 0; i < 4; i++){
    #pragma unroll
    for (int j = 0; j < 4; j++){
      const int cc = wn*64 + j*16 + cl;
      #pragma unroll
      for (int r = 0; r < 4; r++){
        const int rloc = wm*64 + i*16 + rl + r;
        LB[rloc*132 + cc] = f2bf(acc[i][j][r] + bj[j]);
      }
    }
  }
  __syncthreads();
  const int ch = tid & 15;
  #pragma unroll
  for (int it = 0; it < 8; ++it){
    const int rr = (tid >> 4) + it*16;
    bf16x8 v = *(const bf16x8*)&LB[rr*132 + ch*8];
    *(bf16x8*)&eout[(size_t)(bm*128 + rr)*512 + bn*128 + ch*8] = v;
  }
}

// ---------- combine: out[row] += w0*eout[gs0] + w1*eout[gs1] ----------
__global__ __launch_bounds__(256) void moe_combine(
    const ushort* __restrict__ eout, const int2* __restrict__ rowSlots,
    const float2* __restrict__ wts, float* __restrict__ out)
{
  int w = threadIdx.x >> 6, lane = threadIdx.x & 63;
  int row = blockIdx.x * 4 + w;
  int2 rs = rowSlots[row];
  float2 wv = wts[row];
  int d = lane * 8;
  uint4 u0 = *(const uint4*)(eout + (size_t)rs.x*512 + d);
  uint4 u1 = *(const uint4*)(eout + (size_t)rs.y*512 + d);
  float* op = out + (size_t)row*512 + d;
  float4 o0 = *(float4*)op;
  float4 o1 = *(float4*)(op + 4);
  o0.x += wv.x*bf2f((ushort)u0.x)        + wv.y*bf2f((ushort)u1.x);
  o0.y += wv.x*bf2f((ushort)(u0.x>>16))  + wv.y*bf2f((ushort)(u1.x>>16));
  o0.z += wv.x*bf2f((ushort)u0.y)        + wv.y*bf2f((ushort)u1.y);
  o0.w += wv.x*bf2f((ushort)(u0.y>>16))  + wv.y*bf2f((ushort)(u1.y>>16));
  o1.x += wv.x*bf2f((ushort)u0.z)        + wv.y*bf2f((ushort)u1.z);
  o1.y += wv.x*bf2f((ushort)(u0.z>>16))  + wv.y*bf2f((ushort)(u1.z>>16));
  o1.z += wv.x*bf2f((ushort)u0.w)        + wv.y*bf2f((ushort)u1.w);
  o1.w += wv.x*bf2f((ushort)(u0.w>>16))  + wv.y*bf2f((ushort)(u1.w>>16));
  *(float4*)op       = o0;
  *(float4*)(op + 4) = o1;
}

// ---------- attention: one wave per (b,h); qkv f32 [N,1536]; out att split bf16 [N,512] ----------
__global__ __launch_bounds__(64) void attn32(
    const float* __restrict__ qkv, ushort* __restrict__ atthi, ushort* __restrict__ attlo)
{
  int bh = blockIdx.x; int b = bh >> 4, h = bh & 15;
  __shared__ float qs[32][33], ks[32][33], vs[32][33], ps[32][33];
  int lane = threadIdx.x;
  int t = lane >> 1, cb = (lane & 1) * 16;
  const float* src = qkv + (size_t)(b*32 + t)*1536 + h*32 + cb;
  #pragma unroll
  for (int j = 0; j < 16; j += 4){
    float4 q4 = *(const float4*)(src + j);
    float4 k4 = *(const float4*)(src + 512 + j);
    float4 v4 = *(const float4*)(src + 1024 + j);
    qs[t][cb+j]=q4.x; qs[t][cb+j+1]=q4.y; qs[t][cb+j+2]=q4.z; qs[t][cb+j+3]=q4.w;
    ks[t][cb+j]=k4.x; ks[t][cb+j+1]=k4.y; ks[t][cb+j+2]=k4.z; ks[t][cb+j+3]=k4.w;
    vs[t][cb+j]=v4.x; vs[t][cb+j+1]=v4.y; vs[t][cb+j+2]=v4.z; vs[t][cb+j+3]=v4.w;
  }
  __syncthreads();
  const float scale = 0.044194173824159216f; // 1/sqrt(512)
  float sc[16];
  #pragma unroll
  for (int j = 0; j < 16; j++){
    int c = cb + j;
    if (c <= t) {
      float d = 0.f;
      #pragma unroll
      for (int i = 0; i < 32; i++) d += qs[t][i] * ks[c][i];
      sc[j] = d * scale;
    } else sc[j] = -1e30f;
  }
  float mx = -1e30f;
  #pragma unroll
  for (int j = 0; j < 16; j++) mx = fmaxf(mx, sc[j]);
  mx = fmaxf(mx, __shfl_xor(mx, 1));
  float p[16], sum = 0.f;
  #pragma unroll
  for (int j = 0; j < 16; j++){
    int c = cb + j;
    if (c <= t) { p[j] = expf(sc[j] - mx); sum += p[j]; } else p[j] = 0.f;
  }
  sum += __shfl_xor(sum, 1);
  float inv = 1.f / sum;
  #pragma unroll
  for (int j = 0; j < 16; j++) ps[t][cb+j] = p[j] * inv;
  __syncthreads();
  float o[16];
  #pragma unroll
  for (int j = 0; j < 16; j++) o[j] = 0.f;
  for (int s2 = 0; s2 <= t; ++s2){
    float wv = ps[t][s2];
    #pragma unroll
    for (int j = 0; j < 16; j++) o[j] += wv * vs[s2][cb+j];
  }
  size_t base = (size_t)(b*32 + t)*512 + h*32 + cb;
  ushort hu[16], lu[16];
  #pragma unroll
  for (int j = 0; j < 16; j++){
    ushort hi = f2bf(o[j]);
    hu[j] = hi; lu[j] = f2bf(o[j] - bf2f(hi));
  }
  uint4 oh0, oh1, ol0, ol1;
  oh0.x=(uint)hu[0]|((uint)hu[1]<<16);  oh0.y=(uint)hu[2]|((uint)hu[3]<<16);
  oh0.z=(uint)hu[4]|((uint)hu[5]<<16);  oh0.w=(uint)hu[6]|((uint)hu[7]<<16);
  oh1.x=(uint)hu[8]|((uint)hu[9]<<16);  oh1.y=(uint)hu[10]|((uint)hu[11]<<16);
  oh1.z=(uint)hu[12]|((uint)hu[13]<<16);oh1.w=(uint)hu[14]|((uint)hu[15]<<16);
  ol0.x=(uint)lu[0]|((uint)lu[1]<<16);  ol0.y=(uint)lu[2]|((uint)lu[3]<<16);
  ol0.z=(uint)lu[4]|((uint)lu[5]<<16);  ol0.w=(uint)lu[6]|((uint)lu[7]<<16);
  ol1.x=(uint)lu[8]|((uint)lu[9]<<16);  ol1.y=(uint)lu[10]|((uint)lu[11]<<16);
  ol1.z=(uint)lu[12]|((uint)lu[13]<<16);ol1.w=(uint)lu[14]|((uint)lu[15]<<16);
  *(uint4*)(atthi + base)     = oh0;  *(uint4*)(atthi + base + 8) = oh1;
  *(uint4*)(attlo + base)     = ol0;  *(uint4*)(attlo + base + 8) = ol1;
}

// ---------- LN2 + gate: NO atomics. Per-row selection + per-block expert counts ----------
__global__ __launch_bounds__(256) void ln2_gate(
    const float* __restrict__ x1, const float* __restrict__ g, const float* __restrict__ b,
    const float* __restrict__ wgate, ushort* __restrict__ h2,
    int* __restrict__ selp, float2* __restrict__ wts,
    int* __restrict__ blockCnt, float* __restrict__ partials)
{
  __shared__ float wsumLds[4];
  __shared__ int   selLds[4];
  int w = threadIdx.x >> 6, lane = threadIdx.x & 63;
  int row = blockIdx.x * 4 + w;
  const float* xr = x1 + (size_t)row * 512;
  int d = lane * 8;
  float4 a0 = *(const float4*)(xr + d);
  float4 a1 = *(const float4*)(xr + d + 4);
  float v[8] = {a0.x,a0.y,a0.z,a0.w,a1.x,a1.y,a1.z,a1.w};
  float s = 0.f;
  #pragma unroll
  for (int j = 0; j < 8; j++) s += v[j];
  s = wredsum(s);
  float mean = s * (1.f/512.f);
  float q = 0.f;
  #pragma unroll
  for (int j = 0; j < 8; j++){ float t = v[j] - mean; q += t*t; }
  q = wredsum(q);
  float rstd = rsqrtf(q * (1.f/512.f) + 1e-5f);
  float acc0=0.f, acc1=0.f, acc2=0.f, acc3=0.f;
  ushort hu[8];
  #pragma unroll
  for (int j = 0; j < 8; j++){
    float h = (v[j] - mean) * rstd * g[d+j] + b[d+j];
    hu[j] = f2bf(h);
    float4 wgv = *(const float4*)(wgate + (size_t)(d+j)*4);
    acc0 += h * wgv.x; acc1 += h * wgv.y; acc2 += h * wgv.z; acc3 += h * wgv.w;
  }
  uint4 oh;
  oh.x=(uint)hu[0]|((uint)hu[1]<<16); oh.y=(uint)hu[2]|((uint)hu[3]<<16);
  oh.z=(uint)hu[4]|((uint)hu[5]<<16); oh.w=(uint)hu[6]|((uint)hu[7]<<16);
  *(uint4*)(h2 + (size_t)row*512 + d) = oh;
  acc0 = wredsum(acc0); acc1 = wredsum(acc1); acc2 = wredsum(acc2); acc3 = wredsum(acc3);
  if (lane == 0){
    float l[4] = {acc0, acc1, acc2, acc3};
    int i0 = 0;
    for (int e = 1; e < 4; e++) if (l[e] > l[i0]) i0 = e;
    int i1 = -1;
    for (int e = 0; e < 4; e++){ if (e == i0) continue; if (i1 < 0 || l[e] > l[i1]) i1 = e; }
    float e1 = expf(l[i1] - l[i0]);
    float w1v = e1 / (1.f + e1), w0v = 1.f / (1.f + e1);
    int packed = i0 | (i1 << 8);
    selp[row] = packed;
    wts[row]  = make_float2(w0v, w1v);
    selLds[w] = packed;
    wsumLds[w] = l[0] + l[1] + l[2] + l[3];
  }
  __syncthreads();
  if (threadIdx.x < 4){
    int e = threadIdx.x, c = 0;
    #pragma unroll
    for (int i = 0; i < 4; i++){
      int sp = selLds[i];
      c += ((sp & 0xff) == e) + (((sp >> 8) & 0xff) == e);
    }
    blockCnt[e*4096 + blockIdx.x] = c;
  }
  if (threadIdx.x == 0)
    partials[blockIdx.x] = wsumLds[0] + wsumLds[1] + wsumLds[2] + wsumLds[3];
}

// ---------- scan: per-expert block offsets + totals + segments + balance loss ----------
__global__ __launch_bounds__(256) void scan_offsets(
    const int* __restrict__ blockCnt, int* __restrict__ blockOff,
    int* __restrict__ cnt, int* __restrict__ seg,
    const float* __restrict__ partials, float* __restrict__ lossOut)
{
  __shared__ int cntL[4];
  __shared__ float ws4[4];
  int w = threadIdx.x >> 6, lane = threadIdx.x & 63;
  const int* src = blockCnt + w*4096;
  int* dst = blockOff + w*4096;
  int off = 0;
  for (int i = 0; i < 4096; i += 64){
    int v = src[i + lane];
    int orig = v;
    #pragma unroll
    for (int dlt = 1; dlt < 64; dlt <<= 1){
      int t = __shfl_up(v, dlt);
      if (lane >= dlt) v += t;
    }
    dst[i + lane] = off + v - orig;   // exclusive prefix
    off += __shfl(v, 63);
  }
  if (lane == 0){ cnt[w] = off; cntL[w] = off; }
  __syncthreads();
  if (threadIdx.x == 0){
    int t = 0;
    for (int e = 0; e < 4; e++){ seg[e] = t; t += (cntL[e] + 127) >> 7; }
    seg[4] = t;
  }
  // fused balance loss (was gate_reduce)
  float s = 0.f;
  for (int i = threadIdx.x; i < 4096; i += 256) s += partials[i];
  s = wredsum(s);
  if ((threadIdx.x & 63) == 0) ws4[threadIdx.x >> 6] = s;
  __syncthreads();
  if (threadIdx.x == 0){
    float tot = ws4[0] + ws4[1] + ws4[2] + ws4[3];
    float ep = tot * (1.f/65536.f);
    lossOut[0] = ep * logf(ep + 0.1f);
  }
}

// ---------- write compacted routing lists + per-row global slots (deterministic) ----------
__global__ __launch_bounds__(256) void route_write(
    const int* __restrict__ selp, const int* __restrict__ blockOff,
    const int* __restrict__ seg, int* __restrict__ list, int2* __restrict__ rowSlots)
{
  int row = blockIdx.x * 256 + threadIdx.x;
  int g = row & ~3;          // base row of the ln2_gate block (4 rows/block)
  int b = row >> 2;          // ln2_gate block index
  int my = selp[row];
  int e0 = my & 0xff, e1 = (my >> 8) & 0xff;
  int r0 = 0, r1 = 0;
  for (int r = g; r < row; ++r){
    int sp = selp[r];
    int a = sp & 0xff, c = (sp >> 8) & 0xff;
    r0 += (a == e0) + (c == e0);
    r1 += (a == e1) + (c == e1);
  }
  int slot0 = blockOff[e0*4096 + b] + r0;
  int slot1 = blockOff[e1*4096 + b] + r1;
  list[e0*16384 + slot0] = row;
  list[e1*16384 + slot1] = row;
  rowSlots[row] = make_int2(seg[e0]*128 + slot0, seg[e1]*128 + slot1);
}

// ---------- host ----------
extern "C" void kernel_launch(void* const* d_in, const int* in_sizes, int n_in,
                              void* d_out, int out_size, void* d_ws, size_t ws_size,
                              hipStream_t stream)
{
  const float* x     = (const float*)d_in[0];
  const float* ln1g  = (const float*)d_in[1];
  const float* ln1b  = (const float*)d_in[2];
  const float* wq    = (const float*)d_in[3];
  const float* wk    = (const float*)d_in[4];
  const float* wv    = (const float*)d_in[5];
  const float* wproj = (const float*)d_in[6];
  const float* bproj = (const float*)d_in[7];
  const float* ln2g  = (const float*)d_in[8];
  const float* ln2b  = (const float*)d_in[9];
  const float* wgate = (const float*)d_in[10];
  const float* w1    = (const float*)d_in[11];
  const float* b1    = (const float*)d_in[12];
  const float* w2    = (const float*)d_in[13];
  const float* b2    = (const float*)d_in[14];
  float* out = (float*)d_out;

  char* ws = (char*)d_ws;
  // ---- early arena (dead before MoE) ----
  ushort* hHi   = (ushort*)(ws + 0);              // [P0-P1]
  ushort* hLo   = (ushort*)(ws + 16777216);       // [P0-P1]
  ushort* qkvTh = (ushort*)(ws + 33554432);       // [P0-P1]
  ushort* qkvTl = (ushort*)(ws + 35127296);
  ushort* pTh   = (ushort*)(ws + 36700160);       // [P0-P3]
  ushort* pTl   = (ushort*)(ws + 37224448);
  float*  qkvF  = (float*)(ws + 37748736);        // [P1-P2], ends 138412032
  ushort* attHi = (ushort*)(ws + 138412032);      // [P2-P3]
  ushort* attLo = (ushort*)(ws + 155189248);      // [P2-P3], ends 171966464
  // ---- late arena (overlays early, time-disjoint) ----
  ushort* mid   = (ushort*)(ws + 0);              // 136.31 MB [w1-w2], ends 136314880
  ushort* eout  = (ushort*)(ws + 137183744);      // 34.08 MB  [w2-combine], ends 171262464
  // ---- persistent ----
  ushort* h2    = (ushort*)(ws + 171966464);      // [ln2-w1]
  ushort* w1T   = (ushort*)(ws + 188743680);      // [P0-w1]
  ushort* w2T   = (ushort*)(ws + 197132288);      // [P0-w2], ends 205520896
  // ---- routing block: qkvF tail carve [136314880, 137183744) ----
  char* rb = ws + 136314880;
  int*    cnt      = (int*)   (rb + 0);
  int*    seg      = (int*)   (rb + 256);
  int*    list     = (int*)   (rb + 512);         // 262144 B
  int2*   rowSlots = (int2*)  (rb + 262656);      // 131072 B
  float*  partials = (float*) (rb + 524800);      // 16384 B
  int*    selp     = (int*)   (rb + 541184);      // 65536 B
  float2* wts      = (float2*)(rb + 606720);      // 131072 B
  int*    blockCnt = (int*)   (rb + 737792);      // 65536 B
  int*    blockOff = (int*)   (rb + 803328);      // 65536 B -> ends 868864

  // weight prep (transpose + bf16 [split] conversion)
  transpose_qkv<<<dim3(1,16,48), 256, 0, stream>>>(wq, wk, wv, qkvTh, qkvTl);
  transpose_to_bf16<true ><<<dim3(16,16,1), 256, 0, stream>>>(wproj, pTh, pTl, 512, 512);
  transpose_to_bf16<false><<<dim3(64,16,4), 256, 0, stream>>>(w1, w1T, nullptr, 512, 2048);
  transpose_to_bf16<false><<<dim3(16,64,4), 256, 0, stream>>>(w2, w2T, nullptr, 2048, 512);

  // LN1 (split precision)
  ln_split<<<dim3(4096), 256, 0, stream>>>(x, ln1g, ln1b, hHi, hLo);

  // QKV = h @ Wqkv (split-bf16, f32-grade) -> f32 [N,1536]
  gemm_bt<0><<<dim3(128,12), 256, 0, stream>>>(hHi, hLo, qkvTh, qkvTl,
      16384, 1536, 512, qkvF, nullptr, nullptr);

  // attention per (b,h)
  attn32<<<dim3(8192), 64, 0, stream>>>(qkvF, attHi, attLo);

  // x1 = x + att @ Wproj + b_proj (split-bf16) -> d_out f32
  gemm_bt<1><<<dim3(128,4), 256, 0, stream>>>(attHi, attLo, pTh, pTl,
      16384, 512, 512, out, bproj, x);

  // routing: LN2+gate (no atomics) -> scan(+loss) -> compacted lists + rowSlots
  (void)hipMemsetAsync(list, 0, 4*16384*sizeof(int), stream);  // pad slots gather row 0
  ln2_gate<<<dim3(4096), 256, 0, stream>>>(out, ln2g, ln2b, wgate, h2, selp, wts, blockCnt, partials);
  scan_offsets<<<dim3(1), 256, 0, stream>>>(blockCnt, blockOff, cnt, seg, partials, out + 8388608);
  route_write<<<dim3(64), 256, 0, stream>>>(selp, blockOff, seg, list, rowSlots);

  // MoE: merged w1 (gather+gelu -> mid), merged w2 (-> eout), deterministic combine
  gemm_w1<<<dim3(4160), 256, 0, stream>>>(h2,  w1T, b1, mid,  list, seg);
  gemm_w2<<<dim3(1040), 256, 0, stream>>>(mid, w2T, b2, eout, seg);
  moe_combine<<<dim3(4096), 256, 0, stream>>>(eout, rowSlots, wts, out);
}